// Round 1
// baseline (139.280 us; speedup 1.0000x reference)
//
#include <hip/hip_runtime.h>

// ClusterAssignment: q[n,k] = (1/(1+||z_n-c_k||^2)) / sum_k(...)
// N=65536, K=64, D=128, fp32. ALPHA=1.0 -> power = 1 (pow is identity).
//
// Strategy (round 1, fp32 vector):
//   - 1 thread per sample row; 256 threads/block; 256 blocks (1/CU).
//   - centroids staged in LDS (row stride padded 128->132 floats to avoid
//     same-bank pathology in the cnorm pass; main-loop reads are wave-uniform
//     broadcasts so conflict-free regardless).
//   - ||z-c||^2 = ||z||^2 + ||c||^2 - 2 z.c  (no cancellation: diff ~ 256)
//   - z row streamed in 4 chunks of 32 floats (float4) to cap VGPRs.

constexpr int N_SAMP = 65536;
constexpr int K_CL   = 64;
constexpr int D_FT   = 128;
constexpr int CPAD   = 132;   // padded LDS row stride (floats), float4-aligned

__global__ __launch_bounds__(256) void cluster_assign_kernel(
    const float* __restrict__ z,
    const float* __restrict__ cent,
    float* __restrict__ out)
{
    __shared__ float c_lds[K_CL * CPAD];   // ~33 KB
    __shared__ float cnorm_lds[K_CL];

    const int tid = threadIdx.x;

    // ---- cooperative centroid load: 64*128 floats = 2048 float4, 8/thread
    {
        const float4* c4 = reinterpret_cast<const float4*>(cent);
        #pragma unroll
        for (int i = 0; i < 8; ++i) {
            int f   = tid + i * 256;      // float4 index 0..2047
            int row = f >> 5;             // 32 float4 per centroid row
            int col = f & 31;
            float4 v = c4[f];
            *reinterpret_cast<float4*>(&c_lds[row * CPAD + col * 4]) = v;
        }
    }
    __syncthreads();

    // ---- centroid squared norms (wave 0 only; padded stride avoids
    //      the all-lanes-same-bank case)
    if (tid < K_CL) {
        float s = 0.f;
        const float4* crow = reinterpret_cast<const float4*>(&c_lds[tid * CPAD]);
        #pragma unroll
        for (int j = 0; j < 32; ++j) {
            float4 v = crow[j];
            s = fmaf(v.x, v.x, s);
            s = fmaf(v.y, v.y, s);
            s = fmaf(v.z, v.z, s);
            s = fmaf(v.w, v.w, s);
        }
        cnorm_lds[tid] = s;
    }
    __syncthreads();

    const int row = blockIdx.x * 256 + tid;
    const float4* zrow = reinterpret_cast<const float4*>(z) + (size_t)row * (D_FT / 4);

    float acc[K_CL];
    #pragma unroll
    for (int k = 0; k < K_CL; ++k) acc[k] = 0.f;
    float znorm = 0.f;

    // dynamic chunk loop (4 iters) keeps the unrolled body ~20 KB of I$
    for (int chunk = 0; chunk < 4; ++chunk) {
        float4 zv[8];
        #pragma unroll
        for (int j = 0; j < 8; ++j) zv[j] = zrow[chunk * 8 + j];
        #pragma unroll
        for (int j = 0; j < 8; ++j) {
            znorm = fmaf(zv[j].x, zv[j].x, znorm);
            znorm = fmaf(zv[j].y, zv[j].y, znorm);
            znorm = fmaf(zv[j].z, zv[j].z, znorm);
            znorm = fmaf(zv[j].w, zv[j].w, znorm);
        }
        #pragma unroll
        for (int k = 0; k < K_CL; ++k) {
            const float4* crow =
                reinterpret_cast<const float4*>(&c_lds[k * CPAD + chunk * 32]);
            float s = acc[k];
            #pragma unroll
            for (int j = 0; j < 8; ++j) {
                float4 cv = crow[j];   // wave-uniform broadcast read
                s = fmaf(zv[j].x, cv.x, s);
                s = fmaf(zv[j].y, cv.y, s);
                s = fmaf(zv[j].z, cv.z, s);
                s = fmaf(zv[j].w, cv.w, s);
            }
            acc[k] = s;
        }
    }

    // ---- epilogue: num_k = 1/(1+diff_k); q = num / sum(num)
    float ssum = 0.f;
    #pragma unroll
    for (int k = 0; k < K_CL; ++k) {
        float diff = znorm + cnorm_lds[k] - 2.f * acc[k];
        float numv = __builtin_amdgcn_rcpf(1.f + diff);   // 1 ulp, diff >= 0
        acc[k] = numv;
        ssum += numv;
    }
    float inv = __builtin_amdgcn_rcpf(ssum);

    float4* out4 = reinterpret_cast<float4*>(out) + (size_t)row * (K_CL / 4);
    #pragma unroll
    for (int q = 0; q < K_CL / 4; ++q) {
        float4 o;
        o.x = acc[4 * q + 0] * inv;
        o.y = acc[4 * q + 1] * inv;
        o.z = acc[4 * q + 2] * inv;
        o.w = acc[4 * q + 3] * inv;
        out4[q] = o;
    }
}

extern "C" void kernel_launch(void* const* d_in, const int* in_sizes, int n_in,
                              void* d_out, int out_size, void* d_ws, size_t ws_size,
                              hipStream_t stream) {
    const float* z    = (const float*)d_in[0];
    const float* cent = (const float*)d_in[1];
    float* out        = (float*)d_out;

    dim3 grid(N_SAMP / 256);   // 256 blocks, 256 threads: 1 thread = 1 row
    cluster_assign_kernel<<<grid, dim3(256), 0, stream>>>(z, cent, out);
}

// Round 3
// 133.659 us; speedup vs baseline: 1.0421x; 1.0421x over previous
//
#include <hip/hip_runtime.h>

// ClusterAssignment: q[n,k] = (1/(1+||z_n-c_k||^2)) / sum_k(...)
// N=65536, K=64, D=128, fp32. ALPHA=1.0 -> power = 1.
//
// Round 2 (resubmit; round-2 bench hit GPUAcquisitionTimeout):
//   - 4 lanes per sample row; lane's chunk = tid&3 owns 32 features.
//   - 256 thr/block -> 64 rows/block -> 1024 blocks -> 16 waves/CU (4/SIMD).
//   - LDS centroid layout [k][chunk] : k-stride 144 floats (576B),
//     chunk-stride 36 floats (144B). One base VGPR per lane; all inner-loop
//     ds_read_b128 use compile-time offset immediates (max 36400 < 64K).
//     Per-instruction lanes differ only in chunk -> byte offsets 0/16/32/48
//     mod 128 -> 16 distinct banks, 16-lane broadcast groups, conflict-free.
//   - ||z-c||^2 = ||z||^2 + ||c||^2 - 2 z.c ; partial z.c and ||z||^2 reduced
//     over the 4-lane group via __shfl_xor (masks 1,2).
//   - Epilogue: every lane computes all 64 numerators (needed for row sum),
//     then statically selects its 16 output clusters (no runtime reg-array
//     indexing -> no scratch), writes coalesced float4.

constexpr int K_CL   = 64;
constexpr int D_FT   = 128;
constexpr int SLOT_F = 36;            // padded chunk slot (floats): 144 B
constexpr int KSTR_F = 4 * SLOT_F;    // 144 floats per centroid row: 576 B

__global__ __launch_bounds__(256, 4) void cluster_assign_kernel(
    const float* __restrict__ z,
    const float* __restrict__ cent,
    float* __restrict__ out)
{
    __shared__ float c_lds[K_CL * KSTR_F];   // 36864 B
    __shared__ float cnorm_lds[K_CL];

    const int tid = threadIdx.x;

    // ---- stage centroids: 2048 float4, 8 per thread
    {
        const float4* c4 = reinterpret_cast<const float4*>(cent);
        #pragma unroll
        for (int i = 0; i < 8; ++i) {
            int f     = tid + i * 256;     // global float4 index 0..2047
            int k     = f >> 5;            // 32 float4 per centroid row
            int rem   = f & 31;
            int chunk = rem >> 3;
            int j     = rem & 7;
            float4 v  = c4[f];
            *reinterpret_cast<float4*>(
                &c_lds[k * KSTR_F + chunk * SLOT_F + j * 4]) = v;
        }
    }
    __syncthreads();

    // ---- centroid squared norms (one thread per k; one-time cost)
    if (tid < K_CL) {
        float s = 0.f;
        #pragma unroll
        for (int c = 0; c < 4; ++c) {
            const float4* p =
                reinterpret_cast<const float4*>(&c_lds[tid * KSTR_F + c * SLOT_F]);
            #pragma unroll
            for (int j = 0; j < 8; ++j) {
                float4 v = p[j];
                s = fmaf(v.x, v.x, s);
                s = fmaf(v.y, v.y, s);
                s = fmaf(v.z, v.z, s);
                s = fmaf(v.w, v.w, s);
            }
        }
        cnorm_lds[tid] = s;
    }
    __syncthreads();

    const int row   = blockIdx.x * 64 + (tid >> 2);
    const int chunk = tid & 3;

    // ---- load this lane's 32 z features (8 float4)
    const float4* zp = reinterpret_cast<const float4*>(
        z + (size_t)row * D_FT + chunk * 32);
    float4 zv[8];
    #pragma unroll
    for (int j = 0; j < 8; ++j) zv[j] = zp[j];

    float znorm = 0.f;
    #pragma unroll
    for (int j = 0; j < 8; ++j) {
        znorm = fmaf(zv[j].x, zv[j].x, znorm);
        znorm = fmaf(zv[j].y, zv[j].y, znorm);
        znorm = fmaf(zv[j].z, zv[j].z, znorm);
        znorm = fmaf(zv[j].w, zv[j].w, znorm);
    }

    // ---- partial dot products: one lane covers 32 features x 64 clusters
    const float* cb = &c_lds[chunk * SLOT_F];   // per-lane base; offsets static
    float acc[K_CL];
    #pragma unroll
    for (int k = 0; k < K_CL; ++k) {
        const float4* cp = reinterpret_cast<const float4*>(cb + k * KSTR_F);
        float s = 0.f;
        #pragma unroll
        for (int j = 0; j < 8; ++j) {
            float4 cv = cp[j];      // offset: k*576 + j*16 (immediate)
            s = fmaf(zv[j].x, cv.x, s);
            s = fmaf(zv[j].y, cv.y, s);
            s = fmaf(zv[j].z, cv.z, s);
            s = fmaf(zv[j].w, cv.w, s);
        }
        acc[k] = s;
    }

    // ---- reduce over the 4-lane group (butterfly: all 4 lanes get full sums)
    #pragma unroll
    for (int k = 0; k < K_CL; ++k) {
        acc[k] += __shfl_xor(acc[k], 1);
        acc[k] += __shfl_xor(acc[k], 2);
    }
    znorm += __shfl_xor(znorm, 1);
    znorm += __shfl_xor(znorm, 2);

    // ---- numerators + row sum (all 4 lanes redundantly; cheap)
    float ssum = 0.f;
    #pragma unroll
    for (int k = 0; k < K_CL; ++k) {
        float dist = fmaf(-2.f, acc[k], znorm + cnorm_lds[k]);
        float numv = __builtin_amdgcn_rcpf(1.f + dist);
        acc[k] = numv;
        ssum  += numv;
    }
    const float inv = __builtin_amdgcn_rcpf(ssum);

    // ---- lane writes clusters [chunk*16, chunk*16+16) — static selection
    const bool c01   = chunk < 2;          // chunk 0 or 1
    const bool ceven = (chunk & 1) == 0;   // chunk 0 or 2
    float4* outp = reinterpret_cast<float4*>(out + (size_t)row * K_CL + chunk * 16);
    #pragma unroll
    for (int q = 0; q < 4; ++q) {
        float4 o;
        {
            float a0 = ceven ? acc[4*q+0] : acc[16+4*q+0];
            float b0 = ceven ? acc[32+4*q+0] : acc[48+4*q+0];
            o.x = (c01 ? a0 : b0) * inv;
            float a1 = ceven ? acc[4*q+1] : acc[16+4*q+1];
            float b1 = ceven ? acc[32+4*q+1] : acc[48+4*q+1];
            o.y = (c01 ? a1 : b1) * inv;
            float a2 = ceven ? acc[4*q+2] : acc[16+4*q+2];
            float b2 = ceven ? acc[32+4*q+2] : acc[48+4*q+2];
            o.z = (c01 ? a2 : b2) * inv;
            float a3 = ceven ? acc[4*q+3] : acc[16+4*q+3];
            float b3 = ceven ? acc[32+4*q+3] : acc[48+4*q+3];
            o.w = (c01 ? a3 : b3) * inv;
        }
        outp[q] = o;
    }
}

extern "C" void kernel_launch(void* const* d_in, const int* in_sizes, int n_in,
                              void* d_out, int out_size, void* d_ws, size_t ws_size,
                              hipStream_t stream) {
    const float* z    = (const float*)d_in[0];
    const float* cent = (const float*)d_in[1];
    float* out        = (float*)d_out;

    dim3 grid(65536 / 64);   // 1024 blocks; 64 rows/block, 4 lanes/row
    cluster_assign_kernel<<<grid, dim3(256), 0, stream>>>(z, cent, out);
}